// Round 1
// baseline (18.738 us; speedup 1.0000x reference)
//
#include <hip/hip_runtime.h>

// Grid constants from the reference: xOrig = 0 + 1*arange(N)
#define N_GRID 16777216
#define X0_F 0.0f
#define DX_F 1.0f
#define XMAX_F 16777215.0f  // X0 + (N-1)*DX, exactly representable in fp32

// The reference computes sum(roll(mask, ind) * yOrig) where
// mask = [0.5, 0.5, 0, ..., 0]. roll(mask, ind)[k] = mask[(k-ind) mod N],
// so the sum equals  sum_j mask[j] * yOrig[(j+ind) mod N]
//                  = mask[0]*yOrig[ind] + mask[1]*yOrig[(ind+1) mod N].
// O(1) work: a single thread suffices.
__global__ void InterpolatorMaskArgs_3564822856115_kernel(
    const float* __restrict__ x,
    const float* __restrict__ yOrig,
    const float* __restrict__ mask,
    float* __restrict__ out) {
    const float xs = x[0];
    float res = 0.0f;
    // out_of_range = (xs >= XMAX) | (xs < X0) -> 0
    if (!(xs >= XMAX_F || xs < X0_F)) {
        // ind = floor((xs - X0)/DX); with X0=0, DX=1 this is floor(xs).
        int ind = (int)floorf((xs - X0_F) / DX_F);
        int i0 = ind;                    // ind in [0, N-1] here
        int i1 = ind + 1;
        if (i1 >= N_GRID) i1 -= N_GRID;  // roll wraparound semantics
        res = mask[0] * yOrig[i0] + mask[1] * yOrig[i1];
    }
    out[0] = res;
}

extern "C" void kernel_launch(void* const* d_in, const int* in_sizes, int n_in,
                              void* d_out, int out_size, void* d_ws, size_t ws_size,
                              hipStream_t stream) {
    const float* x     = (const float*)d_in[0];
    const float* yOrig = (const float*)d_in[1];
    const float* mask  = (const float*)d_in[2];
    float* out = (float*)d_out;
    InterpolatorMaskArgs_3564822856115_kernel<<<1, 1, 0, stream>>>(x, yOrig, mask, out);
}